// Round 1
// baseline (190.008 us; speedup 1.0000x reference)
//
#include <hip/hip_runtime.h>

#define BATCH 256
#define SEQ   256
#define CDIM  384
#define HDIM  64

typedef __attribute__((ext_vector_type(8))) short bf16x8;
typedef __attribute__((ext_vector_type(4))) float f32x4;

__device__ __forceinline__ unsigned f2bf(float f) {
  union { float f; unsigned u; } v; v.f = f;
  unsigned r = v.u + 0x7FFFu + ((v.u >> 16) & 1u);   // RNE
  return r >> 16;
}

// ---------------------------------------------------------------------------
// kernel 0 (unchanged): WTf = [Wq|Wk|Wv]^T in MFMA fragment order.
//   frag record (ks,nt) = 64 lanes x 16 B; lane (ln15 + 16*quad) holds
//   WT row (nt*16+ln15), cols ks*32+quad*8 .. +7.
// ---------------------------------------------------------------------------
__global__ void wtrans_kernel(const float* __restrict__ Wk, const float* __restrict__ Wq,
                              const float* __restrict__ Wv, unsigned short* __restrict__ WTf) {
  int gid = blockIdx.x * 256 + threadIdx.x;
  if (gid >= 192 * CDIM) return;
  int n = gid / CDIM, kk = gid - n * CDIM;
  const float* W = (n < 64) ? Wq : (n < 128) ? Wk : Wv;
  int nt = n >> 4, ln = n & 15, ks = kk >> 5, sub = (kk >> 3) & 3, j = kk & 7;
  int lane = ln + 16 * sub;
  WTf[(((size_t)ks * 12 + nt) * 64 + lane) * 8 + j] =
      (unsigned short)f2bf(W[kk * HDIM + (n & 63)]);
}

// ---------------------------------------------------------------------------
// kernel 1: FULLY FUSED proj+attention. One block (512 thr = 8 waves) per
// batch; 256 blocks = 1/CU (LDS 147456 B caps occupancy anyway).
//
// Phase A (proj): W staged once -> LDS frag-order (linear 16B copy, overlaps
//   the x preload); wave w packs rows 32w..32w+31 of x[b] into bx[2][12];
//   144 ds_read_b128 per wave, each feeding TWO mfma (row-groups) -> halves
//   LDS traffic per MFMA vs the old proj kernel.  q/k/v never touch HBM.
// Phase B (handoff): after a barrier the W region of LDS is dead; q/k are
//   scattered to QL/KL[256][72] (uint2 packs: C-frag row dim = h channels is
//   contiguous), v transposed into VT[64][264] -- exactly the layouts the
//   verified attn kernel consumed, just built in-place.
// Phase C (attn): verbatim round-4 attn body; wave w handles m-tiles
//   {w, 15-w} -> causal work per wave = NT(w)+NT(15-w) = 18 for every w
//   (perfectly balanced).  q comes from QL instead of global.
// ---------------------------------------------------------------------------
__global__ __launch_bounds__(512, 2) void fused_kernel(
    const float* __restrict__ x, const unsigned short* __restrict__ WTf,
    float* __restrict__ out) {
  __shared__ unsigned short lds[73728];          // 147456 B
  const int tid = threadIdx.x, b = blockIdx.x;
  const int w = tid >> 6, lane = tid & 63;
  const int ln15 = lane & 15, quad = lane >> 4;

  // ---- stage W frags -> LDS: linear 16-B chunks, 18 per thread -----------
  {
    const uint4* src = (const uint4*)WTf;
    uint4* dst = (uint4*)lds;
    #pragma unroll
    for (int i = 0; i < 18; ++i) dst[i * 512 + tid] = src[i * 512 + tid];
  }

  // ---- x preload + pack (overlaps staging): 32 rows/wave, 2 row-groups ---
  bf16x8 bx[2][12];
  {
    const float* xr0 = x + (size_t)(b * 256 + w * 32 + ln15) * CDIM + quad * 8;
    #pragma unroll
    for (int rg = 0; rg < 2; ++rg) {
      const float* xr = xr0 + rg * 16 * CDIM;
      #pragma unroll
      for (int hh = 0; hh < 2; ++hh) {
        float4 A[12];
        #pragma unroll
        for (int j = 0; j < 6; ++j) {
          A[2 * j]     = *(const float4*)(xr + (hh * 6 + j) * 32);
          A[2 * j + 1] = *(const float4*)(xr + (hh * 6 + j) * 32 + 4);
        }
        #pragma unroll
        for (int j = 0; j < 6; ++j) {
          bf16x8 t;
          t[0] = (short)f2bf(A[2 * j].x);     t[1] = (short)f2bf(A[2 * j].y);
          t[2] = (short)f2bf(A[2 * j].z);     t[3] = (short)f2bf(A[2 * j].w);
          t[4] = (short)f2bf(A[2 * j + 1].x); t[5] = (short)f2bf(A[2 * j + 1].y);
          t[6] = (short)f2bf(A[2 * j + 1].z); t[7] = (short)f2bf(A[2 * j + 1].w);
          bx[rg][hh * 6 + j] = t;
        }
      }
    }
  }

  __syncthreads();

  // ---- proj MFMA: each W fragment read once, used for both row-groups ----
  f32x4 acc[2][12];
  #pragma unroll
  for (int rg = 0; rg < 2; ++rg)
    #pragma unroll
    for (int nt = 0; nt < 12; ++nt) acc[rg][nt] = (f32x4){0.f, 0.f, 0.f, 0.f};

  #pragma unroll
  for (int ks = 0; ks < 12; ++ks) {
    #pragma unroll
    for (int nt = 0; nt < 12; ++nt) {
      bf16x8 aw = *(const bf16x8*)&lds[((ks * 12 + nt) * 64 + lane) * 8];
      acc[0][nt] = __builtin_amdgcn_mfma_f32_16x16x32_bf16(aw, bx[0][ks], acc[0][nt], 0, 0, 0);
      acc[1][nt] = __builtin_amdgcn_mfma_f32_16x16x32_bf16(aw, bx[1][ks], acc[1][nt], 0, 0, 0);
    }
  }

  __syncthreads();            // all waves done reading W -> LDS region reusable

  // ---- handoff: q/k/v -> LDS (aliased over the dead W region) ------------
  unsigned short (*QL)[72]  = (unsigned short(*)[72])lds;                 // 36864 B
  unsigned short (*KL)[72]  = (unsigned short(*)[72])(lds + 18432);       // 36864 B
  unsigned short (*VT)[264] = (unsigned short(*)[264])(lds + 36864);      // 33792 B
  unsigned short (*PL)[36]  = (unsigned short(*)[36])(lds + 53760 + w * 576); // 9216 B

  #pragma unroll
  for (int rg = 0; rg < 2; ++rg) {
    const int trow = w * 32 + rg * 16 + ln15;    // C-frag: t indexed by ln15
    #pragma unroll
    for (int nt = 0; nt < 4; ++nt) {             // q channels nt*16+quad*4..+3
      f32x4 a = acc[rg][nt];
      unsigned p0 = f2bf(a[0]) | (f2bf(a[1]) << 16);
      unsigned p1 = f2bf(a[2]) | (f2bf(a[3]) << 16);
      *(uint2*)&QL[trow][nt * 16 + quad * 4] = (uint2){p0, p1};
    }
    #pragma unroll
    for (int nt = 4; nt < 8; ++nt) {             // k
      f32x4 a = acc[rg][nt];
      unsigned p0 = f2bf(a[0]) | (f2bf(a[1]) << 16);
      unsigned p1 = f2bf(a[2]) | (f2bf(a[3]) << 16);
      *(uint2*)&KL[trow][(nt - 4) * 16 + quad * 4] = (uint2){p0, p1};
    }
    #pragma unroll
    for (int nt = 8; nt < 12; ++nt) {            // v, transposed into VT[h][t]
      f32x4 a = acc[rg][nt];
      const int h = (nt - 8) * 16 + quad * 4;
      #pragma unroll
      for (int i = 0; i < 4; ++i)
        VT[h + i][trow] = (unsigned short)f2bf(a[i]);
    }
  }
  __syncthreads();

  // ---- attention: wave w does m-tiles {w, 15-w} (NT sum = 18 for all w) --
  for (int mi = 0; mi < 2; ++mi) {
    const int mt = mi ? (15 - w) : w;
    const int t0 = mt * 16;
    const int NT = (mt | 1) + 1;                 // even # of 16-wide s-tiles

    bf16x8 aq[2];
    #pragma unroll
    for (int ks = 0; ks < 2; ++ks)
      aq[ks] = *(const bf16x8*)&QL[t0 + ln15][ks * 32 + quad * 8];

    float sv[16][4];
    #pragma unroll
    for (int nt = 0; nt < 16; ++nt) {
      if (nt < NT) {
        f32x4 a2 = (f32x4){0.f, 0.f, 0.f, 0.f};
        #pragma unroll
        for (int ks = 0; ks < 2; ++ks) {
          bf16x8 bf = *(const bf16x8*)&KL[nt * 16 + ln15][ks * 32 + quad * 8];
          a2 = __builtin_amdgcn_mfma_f32_16x16x32_bf16(aq[ks], bf, a2, 0, 0, 0);
        }
        int colg = nt * 16 + ln15;
        #pragma unroll
        for (int i = 0; i < 4; ++i) {
          int rowg = t0 + quad * 4 + i;
          sv[nt][i] = (colg <= rowg) ? a2[i] * 0.125f : -3.0e38f;   // 1/sqrt(64)
        }
      }
    }
    float mx[4] = {-3.0e38f, -3.0e38f, -3.0e38f, -3.0e38f};
    #pragma unroll
    for (int nt = 0; nt < 16; ++nt)
      if (nt < NT) {
        #pragma unroll
        for (int i = 0; i < 4; ++i) mx[i] = fmaxf(mx[i], sv[nt][i]);
      }
    #pragma unroll
    for (int i = 0; i < 4; ++i) {                // reduce across 16-lane group
      mx[i] = fmaxf(mx[i], __shfl_xor(mx[i], 8, 64));
      mx[i] = fmaxf(mx[i], __shfl_xor(mx[i], 4, 64));
      mx[i] = fmaxf(mx[i], __shfl_xor(mx[i], 2, 64));
      mx[i] = fmaxf(mx[i], __shfl_xor(mx[i], 1, 64));
    }
    float sm[4] = {0.f, 0.f, 0.f, 0.f};
    #pragma unroll
    for (int nt = 0; nt < 16; ++nt)
      if (nt < NT) {
        #pragma unroll
        for (int i = 0; i < 4; ++i) {
          float e = __expf(sv[nt][i] - mx[i]);
          sv[nt][i] = e;
          sm[i] += e;
        }
      }
    #pragma unroll
    for (int i = 0; i < 4; ++i) {
      sm[i] += __shfl_xor(sm[i], 8, 64);
      sm[i] += __shfl_xor(sm[i], 4, 64);
      sm[i] += __shfl_xor(sm[i], 2, 64);
      sm[i] += __shfl_xor(sm[i], 1, 64);
    }
    float inv[4];
    #pragma unroll
    for (int i = 0; i < 4; ++i) inv[i] = 1.0f / sm[i];

    // PV in 32-wide K chunks via the wave-private P buffer (DS in-order).
    f32x4 o[4];
    #pragma unroll
    for (int ont = 0; ont < 4; ++ont) o[ont] = (f32x4){0.f, 0.f, 0.f, 0.f};

    #pragma unroll
    for (int kc = 0; kc < 8; ++kc) {
      if (kc * 2 < NT) {
        #pragma unroll
        for (int half = 0; half < 2; ++half) {
          int nt = kc * 2 + half;
          #pragma unroll
          for (int i = 0; i < 4; ++i)
            PL[quad * 4 + i][half * 16 + ln15] =
                (unsigned short)f2bf(sv[nt][i] * inv[i]);
        }
        bf16x8 pa = *(const bf16x8*)&PL[ln15][quad * 8];
        #pragma unroll
        for (int ont = 0; ont < 4; ++ont) {
          bf16x8 vb = *(const bf16x8*)&VT[ont * 16 + ln15][kc * 32 + quad * 8];
          o[ont] = __builtin_amdgcn_mfma_f32_16x16x32_bf16(pa, vb, o[ont], 0, 0, 0);
        }
      }
    }

    #pragma unroll
    for (int ont = 0; ont < 4; ++ont) {
      int h = ont * 16 + ln15;
      #pragma unroll
      for (int i = 0; i < 4; ++i)
        out[(size_t)(b * 256 + t0 + quad * 4 + i) * HDIM + h] = o[ont][i];
    }
  }
}

// ---------------------------------------------------------------------------
// ws layout: only WTf remains (147456 B).  q/k/vT intermediates eliminated —
// they live and die inside the fused kernel's LDS.
// ---------------------------------------------------------------------------
extern "C" void kernel_launch(void* const* d_in, const int* in_sizes, int n_in,
                              void* d_out, int out_size, void* d_ws, size_t ws_size,
                              hipStream_t stream) {
  const float* x  = (const float*)d_in[0];
  const float* Wk = (const float*)d_in[1];
  const float* Wq = (const float*)d_in[2];
  const float* Wv = (const float*)d_in[3];
  float* out = (float*)d_out;

  unsigned short* WTf = (unsigned short*)d_ws;   // 147456 B

  wtrans_kernel<<<(192 * CDIM + 255) / 256, 256, 0, stream>>>(Wk, Wq, Wv, WTf);
  fused_kernel<<<256, 512, 0, stream>>>(x, WTf, out);
}

// Round 2
// 181.259 us; speedup vs baseline: 1.0483x; 1.0483x over previous
//
#include <hip/hip_runtime.h>

#define BATCH 256
#define SEQ   256
#define CDIM  384
#define HDIM  64

typedef __attribute__((ext_vector_type(8))) short bf16x8;
typedef __attribute__((ext_vector_type(4))) float f32x4;

__device__ __forceinline__ unsigned f2bf(float f) {
  union { float f; unsigned u; } v; v.f = f;
  unsigned r = v.u + 0x7FFFu + ((v.u >> 16) & 1u);   // RNE
  return r >> 16;
}

// ---------------------------------------------------------------------------
// kernel 0 (unchanged): WTf = [Wq|Wk|Wv]^T in MFMA fragment order.
//   frag record (ks,nt) = 64 lanes x 16 B; lane (ln15 + 16*quad) holds
//   WT row (nt*16+ln15), cols ks*32+quad*8 .. +7.
// ---------------------------------------------------------------------------
__global__ void wtrans_kernel(const float* __restrict__ Wk, const float* __restrict__ Wq,
                              const float* __restrict__ Wv, unsigned short* __restrict__ WTf) {
  int gid = blockIdx.x * 256 + threadIdx.x;
  if (gid >= 192 * CDIM) return;
  int n = gid / CDIM, kk = gid - n * CDIM;
  const float* W = (n < 64) ? Wq : (n < 128) ? Wk : Wv;
  int nt = n >> 4, ln = n & 15, ks = kk >> 5, sub = (kk >> 3) & 3, j = kk & 7;
  int lane = ln + 16 * sub;
  WTf[(((size_t)ks * 12 + nt) * 64 + lane) * 8 + j] =
      (unsigned short)f2bf(W[kk * HDIM + (n & 63)]);
}

// ---------------------------------------------------------------------------
// kernel 1: fused proj+attention, occupancy-fixed.
//   Round-5 post-mortem: 512-thr version ran 89.5 us with ALL pipes <15%
//   busy (Occupancy 21.5% = 2 waves/SIMD) -> latency-bound, not throughput.
//   This version: 1024 thr = 16 waves (4 waves/SIMD, 2x hiding), 16 rows per
//   wave (VGPR ~110 <= 128 so all 16 waves resident), W staged via async
//   global_load_lds width=16 (linear lane pattern; frees LDS-write pipe).
//   Attention: wave w owns m-tile w (max 16 NT-units vs 18 before).
//   LDS 147456 B (W stage) aliased after proj by QL/KL/VT/PL = 125952 B.
// ---------------------------------------------------------------------------
__global__ __launch_bounds__(1024, 4) void fused_kernel(
    const float* __restrict__ x, const unsigned short* __restrict__ WTf,
    float* __restrict__ out) {
  __shared__ __align__(16) unsigned short lds[73728];   // 147456 B
  const int tid = threadIdx.x, b = blockIdx.x;
  const int w = tid >> 6, lane = tid & 63;
  const int ln15 = lane & 15, quad = lane >> 4;

  // ---- stage W frags -> LDS: async DMA, 9 x 1KB chunks per wave ----------
  // dst byte = c*16 = (i*1024 + w*64)*16 + lane*16: wave-uniform base +
  // lane*16 — exactly the global_load_lds write pattern.
  {
    const uint4* src = (const uint4*)WTf;
    #pragma unroll
    for (int i = 0; i < 9; ++i) {
      int c = i * 1024 + tid;
      __builtin_amdgcn_global_load_lds(
          (const __attribute__((address_space(1))) unsigned*)(src + c),
          (__attribute__((address_space(3))) unsigned*)((char*)lds + (size_t)c * 16),
          16, 0, 0);
    }
  }

  // ---- x preload + pack (overlaps W DMA): 16 rows/wave -------------------
  bf16x8 bx[12];
  {
    const float* xr = x + (size_t)(b * 256 + w * 16 + ln15) * CDIM + quad * 8;
    #pragma unroll
    for (int hh = 0; hh < 2; ++hh) {
      float4 A[12];
      #pragma unroll
      for (int j = 0; j < 6; ++j) {
        A[2 * j]     = *(const float4*)(xr + (hh * 6 + j) * 32);
        A[2 * j + 1] = *(const float4*)(xr + (hh * 6 + j) * 32 + 4);
      }
      #pragma unroll
      for (int j = 0; j < 6; ++j) {
        bf16x8 t;
        t[0] = (short)f2bf(A[2 * j].x);     t[1] = (short)f2bf(A[2 * j].y);
        t[2] = (short)f2bf(A[2 * j].z);     t[3] = (short)f2bf(A[2 * j].w);
        t[4] = (short)f2bf(A[2 * j + 1].x); t[5] = (short)f2bf(A[2 * j + 1].y);
        t[6] = (short)f2bf(A[2 * j + 1].z); t[7] = (short)f2bf(A[2 * j + 1].w);
        bx[hh * 6 + j] = t;
      }
    }
  }

  __syncthreads();   // drains vmcnt: W DMA + x loads complete

  // ---- proj MFMA: 144 ds_read_b128 + 144 MFMA per wave -------------------
  f32x4 acc[12];
  #pragma unroll
  for (int nt = 0; nt < 12; ++nt) acc[nt] = (f32x4){0.f, 0.f, 0.f, 0.f};

  #pragma unroll
  for (int ks = 0; ks < 12; ++ks) {
    #pragma unroll
    for (int nt = 0; nt < 12; ++nt) {
      bf16x8 aw = *(const bf16x8*)&lds[((ks * 12 + nt) * 64 + lane) * 8];
      acc[nt] = __builtin_amdgcn_mfma_f32_16x16x32_bf16(aw, bx[ks], acc[nt], 0, 0, 0);
    }
  }

  __syncthreads();            // all waves done reading W -> LDS reusable

  // ---- handoff: q/k/v -> LDS (aliased over the dead W region) ------------
  unsigned short (*QL)[72]  = (unsigned short(*)[72])lds;                 // 36864 B
  unsigned short (*KL)[72]  = (unsigned short(*)[72])(lds + 18432);       // 36864 B
  unsigned short (*VT)[264] = (unsigned short(*)[264])(lds + 36864);      // 33792 B
  unsigned short (*PL)[36]  = (unsigned short(*)[36])(lds + 53760 + w * 576); // 18432 B

  {
    const int trow = w * 16 + ln15;              // C-frag: t indexed by ln15
    #pragma unroll
    for (int nt = 0; nt < 4; ++nt) {             // q channels nt*16+quad*4..+3
      f32x4 a = acc[nt];
      unsigned p0 = f2bf(a[0]) | (f2bf(a[1]) << 16);
      unsigned p1 = f2bf(a[2]) | (f2bf(a[3]) << 16);
      *(uint2*)&QL[trow][nt * 16 + quad * 4] = (uint2){p0, p1};
    }
    #pragma unroll
    for (int nt = 4; nt < 8; ++nt) {             // k
      f32x4 a = acc[nt];
      unsigned p0 = f2bf(a[0]) | (f2bf(a[1]) << 16);
      unsigned p1 = f2bf(a[2]) | (f2bf(a[3]) << 16);
      *(uint2*)&KL[trow][(nt - 4) * 16 + quad * 4] = (uint2){p0, p1};
    }
    #pragma unroll
    for (int nt = 8; nt < 12; ++nt) {            // v, transposed into VT[h][t]
      f32x4 a = acc[nt];
      const int h = (nt - 8) * 16 + quad * 4;
      #pragma unroll
      for (int i = 0; i < 4; ++i)
        VT[h + i][trow] = (unsigned short)f2bf(a[i]);
    }
  }
  __syncthreads();

  // ---- attention: wave w owns m-tile w (one tile per wave) ---------------
  {
    const int mt = w;
    const int t0 = mt * 16;
    const int NT = (mt | 1) + 1;                 // even # of 16-wide s-tiles

    bf16x8 aq[2];
    #pragma unroll
    for (int ks = 0; ks < 2; ++ks)
      aq[ks] = *(const bf16x8*)&QL[t0 + ln15][ks * 32 + quad * 8];

    float sv[16][4];
    #pragma unroll
    for (int nt = 0; nt < 16; ++nt) {
      if (nt < NT) {
        f32x4 a2 = (f32x4){0.f, 0.f, 0.f, 0.f};
        #pragma unroll
        for (int ks = 0; ks < 2; ++ks) {
          bf16x8 bf = *(const bf16x8*)&KL[nt * 16 + ln15][ks * 32 + quad * 8];
          a2 = __builtin_amdgcn_mfma_f32_16x16x32_bf16(aq[ks], bf, a2, 0, 0, 0);
        }
        int colg = nt * 16 + ln15;
        #pragma unroll
        for (int i = 0; i < 4; ++i) {
          int rowg = t0 + quad * 4 + i;
          sv[nt][i] = (colg <= rowg) ? a2[i] * 0.125f : -3.0e38f;   // 1/sqrt(64)
        }
      }
    }
    float mx[4] = {-3.0e38f, -3.0e38f, -3.0e38f, -3.0e38f};
    #pragma unroll
    for (int nt = 0; nt < 16; ++nt)
      if (nt < NT) {
        #pragma unroll
        for (int i = 0; i < 4; ++i) mx[i] = fmaxf(mx[i], sv[nt][i]);
      }
    #pragma unroll
    for (int i = 0; i < 4; ++i) {                // reduce across 16-lane group
      mx[i] = fmaxf(mx[i], __shfl_xor(mx[i], 8, 64));
      mx[i] = fmaxf(mx[i], __shfl_xor(mx[i], 4, 64));
      mx[i] = fmaxf(mx[i], __shfl_xor(mx[i], 2, 64));
      mx[i] = fmaxf(mx[i], __shfl_xor(mx[i], 1, 64));
    }
    float sm[4] = {0.f, 0.f, 0.f, 0.f};
    #pragma unroll
    for (int nt = 0; nt < 16; ++nt)
      if (nt < NT) {
        #pragma unroll
        for (int i = 0; i < 4; ++i) {
          float e = __expf(sv[nt][i] - mx[i]);
          sv[nt][i] = e;
          sm[i] += e;
        }
      }
    #pragma unroll
    for (int i = 0; i < 4; ++i) {
      sm[i] += __shfl_xor(sm[i], 8, 64);
      sm[i] += __shfl_xor(sm[i], 4, 64);
      sm[i] += __shfl_xor(sm[i], 2, 64);
      sm[i] += __shfl_xor(sm[i], 1, 64);
    }
    float inv[4];
    #pragma unroll
    for (int i = 0; i < 4; ++i) inv[i] = 1.0f / sm[i];

    // PV in 32-wide K chunks via the wave-private P buffer (DS in-order).
    f32x4 o[4];
    #pragma unroll
    for (int ont = 0; ont < 4; ++ont) o[ont] = (f32x4){0.f, 0.f, 0.f, 0.f};

    #pragma unroll
    for (int kc = 0; kc < 8; ++kc) {
      if (kc * 2 < NT) {
        #pragma unroll
        for (int half = 0; half < 2; ++half) {
          int nt = kc * 2 + half;
          #pragma unroll
          for (int i = 0; i < 4; ++i)
            PL[quad * 4 + i][half * 16 + ln15] =
                (unsigned short)f2bf(sv[nt][i] * inv[i]);
        }
        bf16x8 pa = *(const bf16x8*)&PL[ln15][quad * 8];
        #pragma unroll
        for (int ont = 0; ont < 4; ++ont) {
          bf16x8 vb = *(const bf16x8*)&VT[ont * 16 + ln15][kc * 32 + quad * 8];
          o[ont] = __builtin_amdgcn_mfma_f32_16x16x32_bf16(pa, vb, o[ont], 0, 0, 0);
        }
      }
    }

    #pragma unroll
    for (int ont = 0; ont < 4; ++ont) {
      int h = ont * 16 + ln15;
      #pragma unroll
      for (int i = 0; i < 4; ++i)
        out[(size_t)(b * 256 + t0 + quad * 4 + i) * HDIM + h] = o[ont][i];
    }
  }
}

// ---------------------------------------------------------------------------
// ws layout: only WTf (147456 B).
// ---------------------------------------------------------------------------
extern "C" void kernel_launch(void* const* d_in, const int* in_sizes, int n_in,
                              void* d_out, int out_size, void* d_ws, size_t ws_size,
                              hipStream_t stream) {
  const float* x  = (const float*)d_in[0];
  const float* Wk = (const float*)d_in[1];
  const float* Wq = (const float*)d_in[2];
  const float* Wv = (const float*)d_in[3];
  float* out = (float*)d_out;

  unsigned short* WTf = (unsigned short*)d_ws;   // 147456 B

  wtrans_kernel<<<(192 * CDIM + 255) / 256, 256, 0, stream>>>(Wk, Wq, Wv, WTf);
  fused_kernel<<<256, 1024, 0, stream>>>(x, WTf, out);
}

// Round 3
// 169.840 us; speedup vs baseline: 1.1187x; 1.0672x over previous
//
#include <hip/hip_runtime.h>

#define BATCH 256
#define SEQ   256
#define CDIM  384
#define HDIM  64

typedef __attribute__((ext_vector_type(8))) short bf16x8;
typedef __attribute__((ext_vector_type(4))) float f32x4;

__device__ __forceinline__ unsigned f2bf(float f) {
  union { float f; unsigned u; } v; v.f = f;
  unsigned r = v.u + 0x7FFFu + ((v.u >> 16) & 1u);   // RNE
  return r >> 16;
}

// ---------------------------------------------------------------------------
// kernel 0 (unchanged): WTf = [Wq|Wk|Wv]^T in MFMA fragment order.
//   frag record (ks,nt) = 64 lanes x 16 B; lane (ln15 + 16*quad) holds
//   WT row (nt*16+ln15), cols ks*32+quad*8 .. +7.
// ---------------------------------------------------------------------------
__global__ void wtrans_kernel(const float* __restrict__ Wk, const float* __restrict__ Wq,
                              const float* __restrict__ Wv, unsigned short* __restrict__ WTf) {
  int gid = blockIdx.x * 256 + threadIdx.x;
  if (gid >= 192 * CDIM) return;
  int n = gid / CDIM, kk = gid - n * CDIM;
  const float* W = (n < 64) ? Wq : (n < 128) ? Wk : Wv;
  int nt = n >> 4, ln = n & 15, ks = kk >> 5, sub = (kk >> 3) & 3, j = kk & 7;
  int lane = ln + 16 * sub;
  WTf[(((size_t)ks * 12 + nt) * 64 + lane) * 8 + j] =
      (unsigned short)f2bf(W[kk * HDIM + (n & 63)]);
}

// ---------------------------------------------------------------------------
// kernel 1: fused proj+attention, PIPELINED.
//   Round-6 post-mortem: 68 us with all pipes <20% busy. Phase 1 (x HBM
//   burst ~16 us) and phase 2 (proj, LDS-bound ~11.5 us) were serialized by
//   the __syncthreads() vmcnt(0) drain.  This version overlaps them:
//   W DMA -> counted s_waitcnt vmcnt(6) (waits ONLY the 9 W DMAs; x chunk 0
//   stays in flight) -> raw s_barrier -> 4-stage ks-pipeline (3 ks/stage,
//   ping-pong P0/P1, fully unrolled, static indices).  x loads stream on the
//   VMEM pipe while ds_read+MFMA stream on LDS/MFMA pipes.
//   sched_barrier(0) pins issue order around the counted wait (rule 18).
//   Handoff + attention unchanged (harness-verified).
// ---------------------------------------------------------------------------
__global__ __launch_bounds__(1024, 4) void fused_kernel(
    const float* __restrict__ x, const unsigned short* __restrict__ WTf,
    float* __restrict__ out) {
  __shared__ __align__(16) unsigned short lds[73728];   // 147456 B
  const int tid = threadIdx.x, b = blockIdx.x;
  const int w = tid >> 6, lane = tid & 63;
  const int ln15 = lane & 15, quad = lane >> 4;

  // ---- 1. W frags -> LDS: async DMA, 9 x 1KB chunks per wave (issued 1st)
  {
    const uint4* src = (const uint4*)WTf;
    #pragma unroll
    for (int i = 0; i < 9; ++i) {
      int c = i * 1024 + tid;
      __builtin_amdgcn_global_load_lds(
          (const __attribute__((address_space(1))) unsigned*)(src + c),
          (__attribute__((address_space(3))) unsigned*)((char*)lds + (size_t)c * 16),
          16, 0, 0);
    }
  }
  __builtin_amdgcn_sched_barrier(0);   // pin: DMAs are the 9 OLDEST vmem ops

  const float* xr = x + (size_t)(b * 256 + w * 16 + ln15) * CDIM + quad * 8;

  // stage buffers: 3 ks per stage = 6 float4
  float4 P0[6], P1[6];

#define LOADST(BUF, BASE)                                                    \
  {                                                                          \
    _Pragma("unroll")                                                        \
    for (int j = 0; j < 3; ++j) {                                            \
      BUF[2 * j]     = *(const float4*)(xr + (BASE + j) * 32);               \
      BUF[2 * j + 1] = *(const float4*)(xr + (BASE + j) * 32 + 4);           \
    }                                                                        \
  }

#define USEST(BUF, BASE)                                                     \
  {                                                                          \
    _Pragma("unroll")                                                        \
    for (int k2 = 0; k2 < 3; ++k2) {                                         \
      float4 a0 = BUF[2 * k2], a1 = BUF[2 * k2 + 1];                         \
      bf16x8 t;                                                              \
      t[0] = (short)f2bf(a0.x); t[1] = (short)f2bf(a0.y);                    \
      t[2] = (short)f2bf(a0.z); t[3] = (short)f2bf(a0.w);                    \
      t[4] = (short)f2bf(a1.x); t[5] = (short)f2bf(a1.y);                    \
      t[6] = (short)f2bf(a1.z); t[7] = (short)f2bf(a1.w);                    \
      _Pragma("unroll")                                                      \
      for (int nt = 0; nt < 12; ++nt) {                                      \
        bf16x8 aw = *(const bf16x8*)&lds[(((BASE + k2) * 12 + nt) * 64 + lane) * 8]; \
        acc[nt] = __builtin_amdgcn_mfma_f32_16x16x32_bf16(aw, t, acc[nt], 0, 0, 0);  \
      }                                                                      \
    }                                                                        \
  }

  // ---- 2. preload x chunk 0 (stays in flight across the W barrier) -------
  LOADST(P0, 0)
  __builtin_amdgcn_sched_barrier(0);

  // counted wait: 9 DMA + 6 x-loads outstanding; vmcnt(6) retires exactly
  // the 9 oldest = all W DMAs.  Raw barrier (NOT __syncthreads: that would
  // drain vmcnt(0) and serialize the x stream behind it).
  asm volatile("s_waitcnt vmcnt(6)" ::: "memory");
  __builtin_amdgcn_s_barrier();
  __builtin_amdgcn_sched_barrier(0);

  // ---- 3. pipelined proj: consume stage s while stage s+1 streams --------
  f32x4 acc[12];
  #pragma unroll
  for (int nt = 0; nt < 12; ++nt) acc[nt] = (f32x4){0.f, 0.f, 0.f, 0.f};

  LOADST(P1, 3)
  USEST(P0, 0)
  LOADST(P0, 6)
  USEST(P1, 3)
  LOADST(P1, 9)
  USEST(P0, 6)
  USEST(P1, 9)

  __syncthreads();            // all waves done reading W -> LDS reusable

  // ---- 4. handoff: q/k/v -> LDS (aliased over the dead W region) ---------
  unsigned short (*QL)[72]  = (unsigned short(*)[72])lds;                 // 36864 B
  unsigned short (*KL)[72]  = (unsigned short(*)[72])(lds + 18432);       // 36864 B
  unsigned short (*VT)[264] = (unsigned short(*)[264])(lds + 36864);      // 33792 B
  unsigned short (*PL)[36]  = (unsigned short(*)[36])(lds + 53760 + w * 576); // 18432 B

  {
    const int trow = w * 16 + ln15;              // C-frag: t indexed by ln15
    #pragma unroll
    for (int nt = 0; nt < 4; ++nt) {             // q channels nt*16+quad*4..+3
      f32x4 a = acc[nt];
      unsigned p0 = f2bf(a[0]) | (f2bf(a[1]) << 16);
      unsigned p1 = f2bf(a[2]) | (f2bf(a[3]) << 16);
      *(uint2*)&QL[trow][nt * 16 + quad * 4] = (uint2){p0, p1};
    }
    #pragma unroll
    for (int nt = 4; nt < 8; ++nt) {             // k
      f32x4 a = acc[nt];
      unsigned p0 = f2bf(a[0]) | (f2bf(a[1]) << 16);
      unsigned p1 = f2bf(a[2]) | (f2bf(a[3]) << 16);
      *(uint2*)&KL[trow][(nt - 4) * 16 + quad * 4] = (uint2){p0, p1};
    }
    #pragma unroll
    for (int nt = 8; nt < 12; ++nt) {            // v, transposed into VT[h][t]
      f32x4 a = acc[nt];
      const int h = (nt - 8) * 16 + quad * 4;
      #pragma unroll
      for (int i = 0; i < 4; ++i)
        VT[h + i][trow] = (unsigned short)f2bf(a[i]);
    }
  }
  __syncthreads();

  // ---- 5. attention: wave w owns m-tile w --------------------------------
  {
    const int mt = w;
    const int t0 = mt * 16;
    const int NT = (mt | 1) + 1;                 // even # of 16-wide s-tiles

    bf16x8 aq[2];
    #pragma unroll
    for (int ks = 0; ks < 2; ++ks)
      aq[ks] = *(const bf16x8*)&QL[t0 + ln15][ks * 32 + quad * 8];

    float sv[16][4];
    #pragma unroll
    for (int nt = 0; nt < 16; ++nt) {
      if (nt < NT) {
        f32x4 a2 = (f32x4){0.f, 0.f, 0.f, 0.f};
        #pragma unroll
        for (int ks = 0; ks < 2; ++ks) {
          bf16x8 bf = *(const bf16x8*)&KL[nt * 16 + ln15][ks * 32 + quad * 8];
          a2 = __builtin_amdgcn_mfma_f32_16x16x32_bf16(aq[ks], bf, a2, 0, 0, 0);
        }
        int colg = nt * 16 + ln15;
        #pragma unroll
        for (int i = 0; i < 4; ++i) {
          int rowg = t0 + quad * 4 + i;
          sv[nt][i] = (colg <= rowg) ? a2[i] * 0.125f : -3.0e38f;   // 1/sqrt(64)
        }
      }
    }
    float mx[4] = {-3.0e38f, -3.0e38f, -3.0e38f, -3.0e38f};
    #pragma unroll
    for (int nt = 0; nt < 16; ++nt)
      if (nt < NT) {
        #pragma unroll
        for (int i = 0; i < 4; ++i) mx[i] = fmaxf(mx[i], sv[nt][i]);
      }
    #pragma unroll
    for (int i = 0; i < 4; ++i) {                // reduce across 16-lane group
      mx[i] = fmaxf(mx[i], __shfl_xor(mx[i], 8, 64));
      mx[i] = fmaxf(mx[i], __shfl_xor(mx[i], 4, 64));
      mx[i] = fmaxf(mx[i], __shfl_xor(mx[i], 2, 64));
      mx[i] = fmaxf(mx[i], __shfl_xor(mx[i], 1, 64));
    }
    float sm[4] = {0.f, 0.f, 0.f, 0.f};
    #pragma unroll
    for (int nt = 0; nt < 16; ++nt)
      if (nt < NT) {
        #pragma unroll
        for (int i = 0; i < 4; ++i) {
          float e = __expf(sv[nt][i] - mx[i]);
          sv[nt][i] = e;
          sm[i] += e;
        }
      }
    #pragma unroll
    for (int i = 0; i < 4; ++i) {
      sm[i] += __shfl_xor(sm[i], 8, 64);
      sm[i] += __shfl_xor(sm[i], 4, 64);
      sm[i] += __shfl_xor(sm[i], 2, 64);
      sm[i] += __shfl_xor(sm[i], 1, 64);
    }
    float inv[4];
    #pragma unroll
    for (int i = 0; i < 4; ++i) inv[i] = 1.0f / sm[i];

    // PV in 32-wide K chunks via the wave-private P buffer (DS in-order).
    f32x4 o[4];
    #pragma unroll
    for (int ont = 0; ont < 4; ++ont) o[ont] = (f32x4){0.f, 0.f, 0.f, 0.f};

    #pragma unroll
    for (int kc = 0; kc < 8; ++kc) {
      if (kc * 2 < NT) {
        #pragma unroll
        for (int half = 0; half < 2; ++half) {
          int nt = kc * 2 + half;
          #pragma unroll
          for (int i = 0; i < 4; ++i)
            PL[quad * 4 + i][half * 16 + ln15] =
                (unsigned short)f2bf(sv[nt][i] * inv[i]);
        }
        bf16x8 pa = *(const bf16x8*)&PL[ln15][quad * 8];
        #pragma unroll
        for (int ont = 0; ont < 4; ++ont) {
          bf16x8 vb = *(const bf16x8*)&VT[ont * 16 + ln15][kc * 32 + quad * 8];
          o[ont] = __builtin_amdgcn_mfma_f32_16x16x32_bf16(pa, vb, o[ont], 0, 0, 0);
        }
      }
    }

    #pragma unroll
    for (int ont = 0; ont < 4; ++ont) {
      int h = ont * 16 + ln15;
      #pragma unroll
      for (int i = 0; i < 4; ++i)
        out[(size_t)(b * 256 + t0 + quad * 4 + i) * HDIM + h] = o[ont][i];
    }
  }
}

// ---------------------------------------------------------------------------
// ws layout: only WTf (147456 B).
// ---------------------------------------------------------------------------
extern "C" void kernel_launch(void* const* d_in, const int* in_sizes, int n_in,
                              void* d_out, int out_size, void* d_ws, size_t ws_size,
                              hipStream_t stream) {
  const float* x  = (const float*)d_in[0];
  const float* Wk = (const float*)d_in[1];
  const float* Wq = (const float*)d_in[2];
  const float* Wv = (const float*)d_in[3];
  float* out = (float*)d_out;

  unsigned short* WTf = (unsigned short*)d_ws;   // 147456 B

  wtrans_kernel<<<(192 * CDIM + 255) / 256, 256, 0, stream>>>(Wk, Wq, Wv, WTf);
  fused_kernel<<<256, 1024, 0, stream>>>(x, WTf, out);
}